// Round 2
// baseline (213.238 us; speedup 1.0000x reference)
//
#include <hip/hip_runtime.h>
#include <hip/hip_bf16.h>
#include <cmath>

#define BB 2
#define SS 2048
#define DD 1024
#define HH 16
#define DHH 64

typedef __bf16 v8bf __attribute__((ext_vector_type(8)));
typedef float f32x4 __attribute__((ext_vector_type(4)));

__device__ __forceinline__ __bf16 f2bf(float f) {
    __hip_bfloat16 h = __float2bfloat16(f);
    return __builtin_bit_cast(__bf16, h);
}

// ---------------------------------------------------------------------------
// Kernel 1: per-head QKV projection.
// grid = (B * S/64, H), block = 256 (4 waves).
// Q,K written [B,H,S,64] bf16 ; V written transposed [B,H,64,S] bf16.
// ---------------------------------------------------------------------------
__global__ __launch_bounds__(256) void qkv_kernel(
    const float* __restrict__ seqs,
    const float* __restrict__ Wq, const float* __restrict__ bq,
    const float* __restrict__ Wk, const float* __restrict__ bk,
    const float* __restrict__ Wv, const float* __restrict__ bv,
    __bf16* __restrict__ q_ws, __bf16* __restrict__ k_ws,
    __bf16* __restrict__ vt_ws)
{
    const int h  = blockIdx.y;
    const int b  = blockIdx.x / (SS / 64);
    const int st = blockIdx.x % (SS / 64);
    const int s0 = st * 64;
    const int tid  = threadIdx.x;
    const int lane = tid & 63;
    const int w    = tid >> 6;      // wave id 0..3
    const int lr   = lane & 15;     // row-in-A / col-in-B,D
    const int lg   = lane >> 4;     // k-group 0..3

    __shared__ __bf16 x_lds[64][72];      // X tile (s-local, d-local), pad 8
    __shared__ __bf16 w_lds[3][64][72];   // Wq/Wk/Wv[h] (e, d)
    __shared__ __bf16 v_lds[64][72];      // V tile transposed (e, s-local)

    // ---- load X tile: rows s0..s0+63, cols h*64..h*64+63 (f32 -> bf16)
#pragma unroll
    for (int i = 0; i < 4; ++i) {
        int idx = tid + i * 256;          // 0..1023
        int r   = idx >> 4;
        int c4  = (idx & 15) * 4;
        float4 v = *reinterpret_cast<const float4*>(
            &seqs[((size_t)b * SS + s0 + r) * DD + h * DHH + c4]);
        x_lds[r][c4 + 0] = f2bf(v.x);
        x_lds[r][c4 + 1] = f2bf(v.y);
        x_lds[r][c4 + 2] = f2bf(v.z);
        x_lds[r][c4 + 3] = f2bf(v.w);
    }
    // ---- load weights (each [64][64] f32)
    const float* Wsrc[3] = { Wq + (size_t)h * DHH * DHH,
                             Wk + (size_t)h * DHH * DHH,
                             Wv + (size_t)h * DHH * DHH };
#pragma unroll
    for (int m = 0; m < 3; ++m) {
#pragma unroll
        for (int i = 0; i < 4; ++i) {
            int idx = tid + i * 256;
            int r   = idx >> 4;
            int c4  = (idx & 15) * 4;
            float4 v = *reinterpret_cast<const float4*>(&Wsrc[m][r * DHH + c4]);
            w_lds[m][r][c4 + 0] = f2bf(v.x);
            w_lds[m][r][c4 + 1] = f2bf(v.y);
            w_lds[m][r][c4 + 2] = f2bf(v.z);
            w_lds[m][r][c4 + 3] = f2bf(v.w);
        }
    }
    __syncthreads();

    // ---- compute: wave w owns output rows w*16 .. w*16+15
    v8bf a0 = *reinterpret_cast<const v8bf*>(&x_lds[w * 16 + lr][lg * 8]);
    v8bf a1 = *reinterpret_cast<const v8bf*>(&x_lds[w * 16 + lr][32 + lg * 8]);

    const float* bias[3] = { bq + h * DHH, bk + h * DHH, bv + h * DHH };

#pragma unroll
    for (int m = 0; m < 3; ++m) {
#pragma unroll
        for (int cg = 0; cg < 4; ++cg) {
            v8bf b0 = *reinterpret_cast<const v8bf*>(&w_lds[m][cg * 16 + lr][lg * 8]);
            v8bf b1 = *reinterpret_cast<const v8bf*>(&w_lds[m][cg * 16 + lr][32 + lg * 8]);
            f32x4 acc = {0.f, 0.f, 0.f, 0.f};
            acc = __builtin_amdgcn_mfma_f32_16x16x32_bf16(a0, b0, acc, 0, 0, 0);
            acc = __builtin_amdgcn_mfma_f32_16x16x32_bf16(a1, b1, acc, 0, 0, 0);
            const int   e   = cg * 16 + lr;
            const float bb_ = bias[m][e];
#pragma unroll
            for (int r = 0; r < 4; ++r) {
                int   row = w * 16 + lg * 4 + r;   // local s
                __bf16 val = f2bf(acc[r] + bb_);
                if (m == 0)
                    q_ws[(((size_t)b * HH + h) * SS + s0 + row) * DHH + e] = val;
                else if (m == 1)
                    k_ws[(((size_t)b * HH + h) * SS + s0 + row) * DHH + e] = val;
                else
                    v_lds[e][row] = val;          // transpose V via LDS
            }
        }
    }
    __syncthreads();

    // ---- write Vt tile: Vt[b,h][e][s0..s0+63], coalesced 16B chunks
#pragma unroll
    for (int i = 0; i < 2; ++i) {
        int idx = tid + i * 256;   // 0..511
        int e   = idx >> 3;
        int c8  = (idx & 7) * 8;
        uint4 v = *reinterpret_cast<const uint4*>(&v_lds[e][c8]);
        *reinterpret_cast<uint4*>(
            &vt_ws[(((size_t)b * HH + h) * DHH + e) * SS + s0 + c8]) = v;
    }
}

// ---------------------------------------------------------------------------
// Kernel 2: flash attention (non-causal), one 64-row Q tile per block.
// grid = (S/64, B*H), block = 256 (4 waves; wave w owns q-rows w*16..+15).
// ---------------------------------------------------------------------------
__global__ __launch_bounds__(256) void flash_kernel(
    const __bf16* __restrict__ q_ws, const __bf16* __restrict__ k_ws,
    const __bf16* __restrict__ vt_ws, float* __restrict__ out)
{
    const int bh = blockIdx.y;          // b*H + h
    const int b  = bh / HH;
    const int h  = bh % HH;
    const int s0 = blockIdx.x * 64;
    const int tid  = threadIdx.x;
    const int lane = tid & 63;
    const int w    = tid >> 6;
    const int lr   = lane & 15;
    const int lg   = lane >> 4;

    __shared__ __bf16 k_lds[64][72];    // K tile  (key, d)
    __shared__ __bf16 vt_lds[64][72];   // Vt tile (e, key-local)
    __shared__ __bf16 p_lds[64][72];    // P tile  (q-local, key-local)

    // ---- Q fragments (held in registers for the whole kernel)
    const size_t qbase = ((size_t)bh * SS + s0) * DHH;
    v8bf qa0 = *reinterpret_cast<const v8bf*>(&q_ws[qbase + (w * 16 + lr) * DHH + lg * 8]);
    v8bf qa1 = *reinterpret_cast<const v8bf*>(&q_ws[qbase + (w * 16 + lr) * DHH + 32 + lg * 8]);

    f32x4 acc[4];
#pragma unroll
    for (int cg = 0; cg < 4; ++cg) acc[cg] = (f32x4){0.f, 0.f, 0.f, 0.f};
    float m_run[4], l_run[4];
#pragma unroll
    for (int r = 0; r < 4; ++r) { m_run[r] = -INFINITY; l_run[r] = 0.f; }

    const size_t kbase  = (size_t)bh * SS * DHH;
    const size_t vtbase = (size_t)bh * DHH * SS;
    constexpr float LOG2E = 1.4426950408889634f;

    for (int kt = 0; kt < SS / 64; ++kt) {
        // ---- stage K tile and Vt tile into LDS (16B per thread per row-chunk)
#pragma unroll
        for (int i = 0; i < 2; ++i) {
            int idx = tid + i * 256;    // 0..511
            int r   = idx >> 3;         // 0..63
            int c8  = (idx & 7) * 8;
            *reinterpret_cast<uint4*>(&k_lds[r][c8]) =
                *reinterpret_cast<const uint4*>(&k_ws[kbase + (size_t)(kt * 64 + r) * DHH + c8]);
            *reinterpret_cast<uint4*>(&vt_lds[r][c8]) =
                *reinterpret_cast<const uint4*>(&vt_ws[vtbase + (size_t)r * SS + kt * 64 + c8]);
        }
        __syncthreads();

        // ---- QK^T : wave computes its 16 q-rows x 64 keys
        f32x4 sc[4];
#pragma unroll
        for (int cg = 0; cg < 4; ++cg) {
            v8bf b0 = *reinterpret_cast<const v8bf*>(&k_lds[cg * 16 + lr][lg * 8]);
            v8bf b1 = *reinterpret_cast<const v8bf*>(&k_lds[cg * 16 + lr][32 + lg * 8]);
            f32x4 a = {0.f, 0.f, 0.f, 0.f};
            a = __builtin_amdgcn_mfma_f32_16x16x32_bf16(qa0, b0, a, 0, 0, 0);
            a = __builtin_amdgcn_mfma_f32_16x16x32_bf16(qa1, b1, a, 0, 0, 0);
            sc[cg] = a * 0.125f;        // 1/sqrt(64)
        }

        // ---- online softmax (row r lives at lane-group lg, reg r)
#pragma unroll
        for (int r = 0; r < 4; ++r) {
            float mx = fmaxf(fmaxf(sc[0][r], sc[1][r]), fmaxf(sc[2][r], sc[3][r]));
            mx = fmaxf(mx, __shfl_xor(mx, 1));
            mx = fmaxf(mx, __shfl_xor(mx, 2));
            mx = fmaxf(mx, __shfl_xor(mx, 4));
            mx = fmaxf(mx, __shfl_xor(mx, 8));
            float m_new = fmaxf(m_run[r], mx);
            float scale = exp2f((m_run[r] - m_new) * LOG2E);
            float rowsum = 0.f;
#pragma unroll
            for (int cg = 0; cg < 4; ++cg) {
                float p = exp2f((sc[cg][r] - m_new) * LOG2E);
                rowsum += p;
                p_lds[w * 16 + lg * 4 + r][cg * 16 + lr] = f2bf(p);
            }
            rowsum += __shfl_xor(rowsum, 1);
            rowsum += __shfl_xor(rowsum, 2);
            rowsum += __shfl_xor(rowsum, 4);
            rowsum += __shfl_xor(rowsum, 8);
            l_run[r] = l_run[r] * scale + rowsum;
            m_run[r] = m_new;
#pragma unroll
            for (int cg = 0; cg < 4; ++cg) acc[cg][r] *= scale;
        }

        // ---- PV : acc += P @ V   (A from p_lds, B from vt_lds)
        v8bf pa0 = *reinterpret_cast<const v8bf*>(&p_lds[w * 16 + lr][lg * 8]);
        v8bf pa1 = *reinterpret_cast<const v8bf*>(&p_lds[w * 16 + lr][32 + lg * 8]);
#pragma unroll
        for (int cg = 0; cg < 4; ++cg) {
            v8bf vb0 = *reinterpret_cast<const v8bf*>(&vt_lds[cg * 16 + lr][lg * 8]);
            v8bf vb1 = *reinterpret_cast<const v8bf*>(&vt_lds[cg * 16 + lr][32 + lg * 8]);
            acc[cg] = __builtin_amdgcn_mfma_f32_16x16x32_bf16(pa0, vb0, acc[cg], 0, 0, 0);
            acc[cg] = __builtin_amdgcn_mfma_f32_16x16x32_bf16(pa1, vb1, acc[cg], 0, 0, 0);
        }
        __syncthreads();   // protect k_lds/vt_lds before next staging
    }

    // ---- epilogue: out[b, s, h*64+e] = acc / l
#pragma unroll
    for (int cg = 0; cg < 4; ++cg) {
#pragma unroll
        for (int r = 0; r < 4; ++r) {
            int srow = s0 + w * 16 + lg * 4 + r;
            int e    = cg * 16 + lr;
            out[((size_t)b * SS + srow) * DD + h * DHH + e] = acc[cg][r] / l_run[r];
        }
    }
}

// ---------------------------------------------------------------------------
extern "C" void kernel_launch(void* const* d_in, const int* in_sizes, int n_in,
                              void* d_out, int out_size, void* d_ws, size_t ws_size,
                              hipStream_t stream)
{
    const float* seqs = (const float*)d_in[0];
    const float* Wq   = (const float*)d_in[1];
    const float* bq   = (const float*)d_in[2];
    const float* Wk   = (const float*)d_in[3];
    const float* bk   = (const float*)d_in[4];
    const float* Wv   = (const float*)d_in[5];
    const float* bv   = (const float*)d_in[6];
    float* out = (float*)d_out;

    const size_t per = (size_t)BB * HH * SS * DHH;  // 4M elems
    __bf16* q_ws  = (__bf16*)d_ws;
    __bf16* k_ws  = q_ws + per;
    __bf16* vt_ws = k_ws + per;

    dim3 gridp(BB * (SS / 64), HH);
    qkv_kernel<<<gridp, 256, 0, stream>>>(seqs, Wq, bq, Wk, bk, Wv, bv,
                                          q_ws, k_ws, vt_ws);
    dim3 gridf(SS / 64, BB * HH);
    flash_kernel<<<gridf, 256, 0, stream>>>(q_ws, k_ws, vt_ws, out);
}

// Round 4
// 184.759 us; speedup vs baseline: 1.1541x; 1.1541x over previous
//
#include <hip/hip_runtime.h>
#include <hip/hip_bf16.h>
#include <cmath>

#define BB 2
#define SS 2048
#define DD 1024
#define HH 16
#define DHH 64
#define NT (SS / 64)

typedef __bf16 v8bf __attribute__((ext_vector_type(8)));
typedef float f32x4 __attribute__((ext_vector_type(4)));

static __device__ __forceinline__ __bf16 f2bf(float f) {
    __hip_bfloat16 h = __float2bfloat16(f);
    return __builtin_bit_cast(__bf16, h);
}
static __device__ __forceinline__ unsigned pk2(float a, float b) {
    unsigned short ua = __builtin_bit_cast(unsigned short, f2bf(a));
    unsigned short ub = __builtin_bit_cast(unsigned short, f2bf(b));
    return (unsigned)ua | ((unsigned)ub << 16);
}

// ---------------------------------------------------------------------------
// Kernel 1: per-head QKV projection.
// grid = (B * S/64, H), block = 256 (4 waves).
// Q (pre-scaled by 1/sqrt(DH)) and K written [B,H,S,64] bf16;
// V written transposed [B,H,64,S] bf16.
// ---------------------------------------------------------------------------
__global__ __launch_bounds__(256) void qkv_kernel(
    const float* __restrict__ seqs,
    const float* __restrict__ Wq, const float* __restrict__ bq,
    const float* __restrict__ Wk, const float* __restrict__ bk,
    const float* __restrict__ Wv, const float* __restrict__ bv,
    __bf16* __restrict__ q_ws, __bf16* __restrict__ k_ws,
    __bf16* __restrict__ vt_ws)
{
    const int h  = blockIdx.y;
    const int b  = blockIdx.x / (SS / 64);
    const int st = blockIdx.x % (SS / 64);
    const int s0 = st * 64;
    const int tid  = threadIdx.x;
    const int lane = tid & 63;
    const int w    = tid >> 6;
    const int lr   = lane & 15;
    const int lg   = lane >> 4;

    __shared__ __bf16 x_lds[64][72];
    __shared__ __bf16 w_lds[3][64][72];
    __shared__ __bf16 v_lds[64][72];

    // ---- stage X tile (f32 -> packed bf16x2 -> 8B LDS writes)
#pragma unroll
    for (int i = 0; i < 4; ++i) {
        int idx = tid + i * 256;
        int r   = idx >> 4;
        int c4  = (idx & 15) * 4;
        float4 v = *reinterpret_cast<const float4*>(
            &seqs[((size_t)b * SS + s0 + r) * DD + h * DHH + c4]);
        uint2 u;
        u.x = pk2(v.x, v.y);
        u.y = pk2(v.z, v.w);
        *reinterpret_cast<uint2*>(&x_lds[r][c4]) = u;
    }
    // ---- stage weights
    const float* Wsrc[3] = { Wq + (size_t)h * DHH * DHH,
                             Wk + (size_t)h * DHH * DHH,
                             Wv + (size_t)h * DHH * DHH };
#pragma unroll
    for (int m = 0; m < 3; ++m) {
#pragma unroll
        for (int i = 0; i < 4; ++i) {
            int idx = tid + i * 256;
            int r   = idx >> 4;
            int c4  = (idx & 15) * 4;
            float4 v = *reinterpret_cast<const float4*>(&Wsrc[m][r * DHH + c4]);
            uint2 u;
            u.x = pk2(v.x, v.y);
            u.y = pk2(v.z, v.w);
            *reinterpret_cast<uint2*>(&w_lds[m][r][c4]) = u;
        }
    }
    __syncthreads();

    v8bf a0 = *reinterpret_cast<const v8bf*>(&x_lds[w * 16 + lr][lg * 8]);
    v8bf a1 = *reinterpret_cast<const v8bf*>(&x_lds[w * 16 + lr][32 + lg * 8]);

    const float* bias[3] = { bq + h * DHH, bk + h * DHH, bv + h * DHH };

#pragma unroll
    for (int m = 0; m < 3; ++m) {
#pragma unroll
        for (int cg = 0; cg < 4; ++cg) {
            v8bf b0 = *reinterpret_cast<const v8bf*>(&w_lds[m][cg * 16 + lr][lg * 8]);
            v8bf b1 = *reinterpret_cast<const v8bf*>(&w_lds[m][cg * 16 + lr][32 + lg * 8]);
            f32x4 acc = {0.f, 0.f, 0.f, 0.f};
            acc = __builtin_amdgcn_mfma_f32_16x16x32_bf16(a0, b0, acc, 0, 0, 0);
            acc = __builtin_amdgcn_mfma_f32_16x16x32_bf16(a1, b1, acc, 0, 0, 0);
            const int   e   = cg * 16 + lr;
            const float bb_ = bias[m][e];
            if (m == 2) {
                // V: transpose via LDS, packed 8B write (rows of v_lds[e][...])
                uint2 u;
                u.x = pk2(acc[0] + bb_, acc[1] + bb_);
                u.y = pk2(acc[2] + bb_, acc[3] + bb_);
                *reinterpret_cast<uint2*>(&v_lds[e][w * 16 + lg * 4]) = u;
            } else {
                const float sc = (m == 0) ? 0.125f : 1.0f;  // fold 1/sqrt(64) into Q
#pragma unroll
                for (int r = 0; r < 4; ++r) {
                    int row = w * 16 + lg * 4 + r;
                    __bf16 val = f2bf((acc[r] + bb_) * sc);
                    if (m == 0)
                        q_ws[(((size_t)b * HH + h) * SS + s0 + row) * DHH + e] = val;
                    else
                        k_ws[(((size_t)b * HH + h) * SS + s0 + row) * DHH + e] = val;
                }
            }
        }
    }
    __syncthreads();

    // ---- write Vt tile coalesced
#pragma unroll
    for (int i = 0; i < 2; ++i) {
        int idx = tid + i * 256;
        int e   = idx >> 3;
        int c8  = (idx & 7) * 8;
        uint4 v = *reinterpret_cast<const uint4*>(&v_lds[e][c8]);
        *reinterpret_cast<uint4*>(
            &vt_ws[(((size_t)b * HH + h) * DHH + e) * SS + s0 + c8]) = v;
    }
}

// ---------------------------------------------------------------------------
// Kernel 2: flash attention, swapped-QK^T lane-local softmax,
// global_load_lds staging into XOR-swizzled double-buffered K/V tiles.
// grid = (S/64, B*H), block = 256 (4 waves).
// ---------------------------------------------------------------------------
__global__ __launch_bounds__(256) void flash_kernel(
    const __bf16* __restrict__ q_ws, const __bf16* __restrict__ k_ws,
    const __bf16* __restrict__ vt_ws, float* __restrict__ out)
{
    const int bh = blockIdx.y;
    const int b  = bh / HH;
    const int h  = bh % HH;
    const int s0 = blockIdx.x * 64;
    const int tid  = threadIdx.x;
    const int lane = tid & 63;
    const int w    = tid >> 6;
    const int lr   = lane & 15;
    const int lg   = lane >> 4;

    // [buf][K=0/V=1][64 rows][64 elems], linear (contents XOR-swizzled:
    // elem_off = row*64 + (col ^ ((row&7)*8)) at 8-elem granularity)
    __shared__ __bf16 kv_lds[2][2][64 * 64];
    __shared__ __bf16 p_lds[64][72];

    const size_t qbase = ((size_t)bh * SS + s0) * DHH;
    v8bf qa0 = *reinterpret_cast<const v8bf*>(&q_ws[qbase + (w * 16 + lr) * DHH + lg * 8]);
    v8bf qa1 = *reinterpret_cast<const v8bf*>(&q_ws[qbase + (w * 16 + lr) * DHH + 32 + lg * 8]);

    const __bf16* kg = k_ws  + (size_t)bh * SS * DHH;   // [S][64]
    const __bf16* vg = vt_ws + (size_t)bh * DHH * SS;   // [64][S]

    f32x4 acc[4];
#pragma unroll
    for (int cg = 0; cg < 4; ++cg) acc[cg] = (f32x4){0.f, 0.f, 0.f, 0.f};
    float m_run = -INFINITY;
    float l_run = 0.f;
    constexpr float LOG2E = 1.4426950408889634f;

    const int srow = lane >> 3;                 // chunk-local row 0..7
    const int scol = 8 * ((lane & 7) ^ srow);   // inverse-swizzled elem col

    // Stage tile kt into buffer `buf`: waves 0,1 stage K; waves 2,3 stage V.
    // LDS dest is linear (base + lane*16); global src is pre-swizzled.
    auto stage = [&](int buf, int kt) {
#pragma unroll
        for (int j = 0; j < 4; ++j) {
            int c   = w * 4 + j;       // 0..15
            int sub = c & 7;           // 8-row group
            int row = sub * 8 + srow;
            if (c < 8) {
                const __bf16* src = kg + (size_t)(kt * 64 + row) * DHH + scol;
                __builtin_amdgcn_global_load_lds(
                    (const __attribute__((address_space(1))) unsigned int*)src,
                    (__attribute__((address_space(3))) unsigned int*)&kv_lds[buf][0][sub * 512],
                    16, 0, 0);
            } else {
                const __bf16* src = vg + (size_t)row * SS + kt * 64 + scol;
                __builtin_amdgcn_global_load_lds(
                    (const __attribute__((address_space(1))) unsigned int*)src,
                    (__attribute__((address_space(3))) unsigned int*)&kv_lds[buf][1][sub * 512],
                    16, 0, 0);
            }
        }
    };

    stage(0, 0);
    __syncthreads();

    int cur = 0;
    for (int kt = 0; kt < NT; ++kt) {
        if (kt + 1 < NT) stage(cur ^ 1, kt + 1);   // issue-early prefetch

        const __bf16* kb = &kv_lds[cur][0][0];
        const __bf16* vb = &kv_lds[cur][1][0];
        const int sw = (lr & 7);                   // read-side swizzle key

        // ---- QK^T swapped: D[k][q], lane holds 16 scores of q-row (w*16+lr)
        f32x4 sc[4];
#pragma unroll
        for (int cg = 0; cg < 4; ++cg) {
            int row = cg * 16 + lr;
            v8bf a0 = *reinterpret_cast<const v8bf*>(&kb[row * 64 + 8 * (lg ^ sw)]);
            v8bf a1 = *reinterpret_cast<const v8bf*>(&kb[row * 64 + 8 * ((4 + lg) ^ sw)]);
            f32x4 t = {0.f, 0.f, 0.f, 0.f};
            t = __builtin_amdgcn_mfma_f32_16x16x32_bf16(a0, qa0, t, 0, 0, 0);
            t = __builtin_amdgcn_mfma_f32_16x16x32_bf16(a1, qa1, t, 0, 0, 0);
            sc[cg] = t;
        }

        // ---- lane-local online softmax (q = w*16+lr; scores pre-scaled via Q)
        float mloc = sc[0][0];
#pragma unroll
        for (int cg = 0; cg < 4; ++cg)
#pragma unroll
            for (int r = 0; r < 4; ++r) mloc = fmaxf(mloc, sc[cg][r]);
        mloc = fmaxf(mloc, __shfl_xor(mloc, 16));
        mloc = fmaxf(mloc, __shfl_xor(mloc, 32));
        float m_new = fmaxf(m_run, mloc);
        float corr  = exp2f((m_run - m_new) * LOG2E);
        float rs = 0.f;
#pragma unroll
        for (int cg = 0; cg < 4; ++cg) {
            float p0 = exp2f((sc[cg][0] - m_new) * LOG2E);
            float p1 = exp2f((sc[cg][1] - m_new) * LOG2E);
            float p2 = exp2f((sc[cg][2] - m_new) * LOG2E);
            float p3 = exp2f((sc[cg][3] - m_new) * LOG2E);
            rs += (p0 + p1) + (p2 + p3);
            uint2 u;
            u.x = pk2(p0, p1);
            u.y = pk2(p2, p3);
            // P[q][k]: q-row = w*16+lr, k = cg*16 + lg*4 + {0..3}
            *reinterpret_cast<uint2*>(&p_lds[w * 16 + lr][cg * 16 + lg * 4]) = u;
        }
        rs += __shfl_xor(rs, 16);
        rs += __shfl_xor(rs, 32);
        l_run = l_run * corr + rs;
        m_run = m_new;

        // ---- rescale accumulator (acc rows are q-local lg*4+r -> broadcast)
        float cb[4];
#pragma unroll
        for (int r = 0; r < 4; ++r) cb[r] = __shfl(corr, lg * 4 + r);
#pragma unroll
        for (int cg = 0; cg < 4; ++cg)
#pragma unroll
            for (int r = 0; r < 4; ++r) acc[cg][r] *= cb[r];

        // ---- PV: acc += P @ V
        v8bf pa0 = *reinterpret_cast<const v8bf*>(&p_lds[w * 16 + lr][lg * 8]);
        v8bf pa1 = *reinterpret_cast<const v8bf*>(&p_lds[w * 16 + lr][32 + lg * 8]);
#pragma unroll
        for (int cg = 0; cg < 4; ++cg) {
            int row = cg * 16 + lr;
            v8bf b0 = *reinterpret_cast<const v8bf*>(&vb[row * 64 + 8 * (lg ^ sw)]);
            v8bf b1 = *reinterpret_cast<const v8bf*>(&vb[row * 64 + 8 * ((4 + lg) ^ sw)]);
            acc[cg] = __builtin_amdgcn_mfma_f32_16x16x32_bf16(pa0, b0, acc[cg], 0, 0, 0);
            acc[cg] = __builtin_amdgcn_mfma_f32_16x16x32_bf16(pa1, b1, acc[cg], 0, 0, 0);
        }

        __syncthreads();   // drains prefetch (vmcnt 0) + protects cur^1 reuse
        cur ^= 1;
    }

    // ---- epilogue
    float linv[4];
#pragma unroll
    for (int r = 0; r < 4; ++r) linv[r] = 1.0f / __shfl(l_run, lg * 4 + r);
#pragma unroll
    for (int cg = 0; cg < 4; ++cg)
#pragma unroll
        for (int r = 0; r < 4; ++r) {
            int sr = s0 + w * 16 + lg * 4 + r;
            int e  = cg * 16 + lr;
            out[((size_t)b * SS + sr) * DD + h * DHH + e] = acc[cg][r] * linv[r];
        }
}

// ---------------------------------------------------------------------------
extern "C" void kernel_launch(void* const* d_in, const int* in_sizes, int n_in,
                              void* d_out, int out_size, void* d_ws, size_t ws_size,
                              hipStream_t stream)
{
    const float* seqs = (const float*)d_in[0];
    const float* Wq   = (const float*)d_in[1];
    const float* bq   = (const float*)d_in[2];
    const float* Wk   = (const float*)d_in[3];
    const float* bk   = (const float*)d_in[4];
    const float* Wv   = (const float*)d_in[5];
    const float* bv   = (const float*)d_in[6];
    float* out = (float*)d_out;

    const size_t per = (size_t)BB * HH * SS * DHH;
    __bf16* q_ws  = (__bf16*)d_ws;
    __bf16* k_ws  = q_ws + per;
    __bf16* vt_ws = k_ws + per;

    dim3 gridp(BB * (SS / 64), HH);
    qkv_kernel<<<gridp, 256, 0, stream>>>(seqs, Wq, bq, Wk, bk, Wv, bv,
                                          q_ws, k_ws, vt_ws);
    dim3 gridf(SS / 64, BB * HH);
    flash_kernel<<<gridf, 256, 0, stream>>>(q_ws, k_ws, vt_ws, out);
}

// Round 5
// 156.870 us; speedup vs baseline: 1.3593x; 1.1778x over previous
//
#include <hip/hip_runtime.h>
#include <hip/hip_bf16.h>
#include <cmath>

#define BB 2
#define SS 2048
#define DD 1024
#define HH 16
#define DHH 64
#define NT (SS / 64)
#define QBLK 128

typedef __bf16 v8bf __attribute__((ext_vector_type(8)));
typedef float f32x4 __attribute__((ext_vector_type(4)));

static __device__ __forceinline__ __bf16 f2bf(float f) {
    __hip_bfloat16 h = __float2bfloat16(f);
    return __builtin_bit_cast(__bf16, h);
}
static __device__ __forceinline__ unsigned pk2(float a, float b) {
    unsigned short ua = __builtin_bit_cast(unsigned short, f2bf(a));
    unsigned short ub = __builtin_bit_cast(unsigned short, f2bf(b));
    return (unsigned)ua | ((unsigned)ub << 16);
}

// Q path is pre-scaled by 1/sqrt(64) * log2(e) so flash uses exp2 directly.
#define SCQ 0.1803368801111204f  // 0.125 * 1.4426950408889634

// ---------------------------------------------------------------------------
// Kernel 1: per-head QKV projection.
// grid = (B * S/64, H), block = 256 (4 waves).
// Q (log2-scaled) and K written [B,H,S,64] bf16 via packed uint2 stores;
// V written transposed [B,H,64,S] bf16.
// ---------------------------------------------------------------------------
__global__ __launch_bounds__(256) void qkv_kernel(
    const float* __restrict__ seqs,
    const float* __restrict__ Wq, const float* __restrict__ bq,
    const float* __restrict__ Wk, const float* __restrict__ bk,
    const float* __restrict__ Wv, const float* __restrict__ bv,
    __bf16* __restrict__ q_ws, __bf16* __restrict__ k_ws,
    __bf16* __restrict__ vt_ws)
{
    const int h  = blockIdx.y;
    const int b  = blockIdx.x / (SS / 64);
    const int st = blockIdx.x % (SS / 64);
    const int s0 = st * 64;
    const int tid  = threadIdx.x;
    const int lane = tid & 63;
    const int w    = tid >> 6;
    const int lr   = lane & 15;
    const int lg   = lane >> 4;

    __shared__ __bf16 x_lds[64][72];
    __shared__ __bf16 w_lds[3][64][72];
    __shared__ __bf16 v_lds[64][72];

    // ---- stage X tile (f32 -> packed bf16x2 -> 8B LDS writes)
#pragma unroll
    for (int i = 0; i < 4; ++i) {
        int idx = tid + i * 256;
        int r   = idx >> 4;
        int c4  = (idx & 15) * 4;
        float4 v = *reinterpret_cast<const float4*>(
            &seqs[((size_t)b * SS + s0 + r) * DD + h * DHH + c4]);
        uint2 u;
        u.x = pk2(v.x, v.y);
        u.y = pk2(v.z, v.w);
        *reinterpret_cast<uint2*>(&x_lds[r][c4]) = u;
    }
    // ---- stage weights (Wq pre-scaled by SCQ)
    const float* Wsrc[3] = { Wq + (size_t)h * DHH * DHH,
                             Wk + (size_t)h * DHH * DHH,
                             Wv + (size_t)h * DHH * DHH };
#pragma unroll
    for (int m = 0; m < 3; ++m) {
        const float ws_ = (m == 0) ? SCQ : 1.0f;
#pragma unroll
        for (int i = 0; i < 4; ++i) {
            int idx = tid + i * 256;
            int r   = idx >> 4;
            int c4  = (idx & 15) * 4;
            float4 v = *reinterpret_cast<const float4*>(&Wsrc[m][r * DHH + c4]);
            uint2 u;
            u.x = pk2(v.x * ws_, v.y * ws_);
            u.y = pk2(v.z * ws_, v.w * ws_);
            *reinterpret_cast<uint2*>(&w_lds[m][r][c4]) = u;
        }
    }
    __syncthreads();

    v8bf a0 = *reinterpret_cast<const v8bf*>(&x_lds[w * 16 + lr][lg * 8]);
    v8bf a1 = *reinterpret_cast<const v8bf*>(&x_lds[w * 16 + lr][32 + lg * 8]);

    // ---- Q, K: swapped operands -> D[e][s]; lane holds 4 consecutive e at
    //      fixed s = w*16+lr  -> packed uint2 global stores.
#pragma unroll
    for (int m = 0; m < 2; ++m) {
        const float* bias = (m == 0) ? bq + h * DHH : bk + h * DHH;
        const float bsc   = (m == 0) ? SCQ : 1.0f;
        __bf16* dst = (m == 0) ? q_ws : k_ws;
#pragma unroll
        for (int cg = 0; cg < 4; ++cg) {
            v8bf b0 = *reinterpret_cast<const v8bf*>(&w_lds[m][cg * 16 + lr][lg * 8]);
            v8bf b1 = *reinterpret_cast<const v8bf*>(&w_lds[m][cg * 16 + lr][32 + lg * 8]);
            f32x4 acc = {0.f, 0.f, 0.f, 0.f};
            acc = __builtin_amdgcn_mfma_f32_16x16x32_bf16(b0, a0, acc, 0, 0, 0);
            acc = __builtin_amdgcn_mfma_f32_16x16x32_bf16(b1, a1, acc, 0, 0, 0);
            const int e0 = cg * 16 + lg * 4;
            uint2 u;
            u.x = pk2(acc[0] + bias[e0 + 0] * bsc, acc[1] + bias[e0 + 1] * bsc);
            u.y = pk2(acc[2] + bias[e0 + 2] * bsc, acc[3] + bias[e0 + 3] * bsc);
            *reinterpret_cast<uint2*>(
                &dst[(((size_t)b * HH + h) * SS + s0 + w * 16 + lr) * DHH + e0]) = u;
        }
    }

    // ---- V: original orientation -> LDS transpose -> coalesced Vt store
    {
        const float* bias = bv + h * DHH;
#pragma unroll
        for (int cg = 0; cg < 4; ++cg) {
            v8bf b0 = *reinterpret_cast<const v8bf*>(&w_lds[2][cg * 16 + lr][lg * 8]);
            v8bf b1 = *reinterpret_cast<const v8bf*>(&w_lds[2][cg * 16 + lr][32 + lg * 8]);
            f32x4 acc = {0.f, 0.f, 0.f, 0.f};
            acc = __builtin_amdgcn_mfma_f32_16x16x32_bf16(a0, b0, acc, 0, 0, 0);
            acc = __builtin_amdgcn_mfma_f32_16x16x32_bf16(a1, b1, acc, 0, 0, 0);
            const int   e   = cg * 16 + lr;
            const float bb_ = bias[e];
            uint2 u;
            u.x = pk2(acc[0] + bb_, acc[1] + bb_);
            u.y = pk2(acc[2] + bb_, acc[3] + bb_);
            *reinterpret_cast<uint2*>(&v_lds[e][w * 16 + lg * 4]) = u;
        }
    }
    __syncthreads();

#pragma unroll
    for (int i = 0; i < 2; ++i) {
        int idx = tid + i * 256;
        int e   = idx >> 3;
        int c8  = (idx & 7) * 8;
        uint4 v = *reinterpret_cast<const uint4*>(&v_lds[e][c8]);
        *reinterpret_cast<uint4*>(
            &vt_ws[(((size_t)b * HH + h) * DHH + e) * SS + s0 + c8]) = v;
    }
}

// ---------------------------------------------------------------------------
// Kernel 2: flash attention. 8 waves, QBLK=128 q-rows per block.
// Swapped QK^T (lane-local softmax, log2 domain), defer-max, setprio,
// global_load_lds staging into XOR-swizzled double-buffered K/V tiles.
// grid = (S/128, B*H), block = 512.
// ---------------------------------------------------------------------------
__global__ __launch_bounds__(512) void flash_kernel(
    const __bf16* __restrict__ q_ws, const __bf16* __restrict__ k_ws,
    const __bf16* __restrict__ vt_ws, float* __restrict__ out)
{
    const int bh = blockIdx.y;
    const int b  = bh / HH;
    const int h  = bh % HH;
    const int s0 = blockIdx.x * QBLK;
    const int tid  = threadIdx.x;
    const int lane = tid & 63;
    const int w    = tid >> 6;        // wave 0..7
    const int lr   = lane & 15;
    const int lg   = lane >> 4;

    // [buf][K=0/V=1][64x64], linear; contents XOR-swizzled at 8-elem grain:
    // element [row][col] lives at row*64 + (col ^ ((row&7)*8))
    __shared__ __bf16 kv_lds[2][2][64 * 64];
    __shared__ __bf16 p_lds[QBLK][72];

    // Q fragments: wave w owns q-rows s0 + w*16 .. +15
    const size_t qbase = ((size_t)bh * SS + s0) * DHH;
    v8bf qa0 = *reinterpret_cast<const v8bf*>(&q_ws[qbase + (w * 16 + lr) * DHH + lg * 8]);
    v8bf qa1 = *reinterpret_cast<const v8bf*>(&q_ws[qbase + (w * 16 + lr) * DHH + 32 + lg * 8]);

    const __bf16* kg = k_ws  + (size_t)bh * SS * DHH;   // [S][64]
    const __bf16* vg = vt_ws + (size_t)bh * DHH * SS;   // [64][S]

    f32x4 acc[4];
#pragma unroll
    for (int cg = 0; cg < 4; ++cg) acc[cg] = (f32x4){0.f, 0.f, 0.f, 0.f};
    float m_run = -INFINITY;
    float l_run = 0.f;

    const int srow = lane >> 3;                 // 0..7 within 8-row group
    const int scol = 8 * ((lane & 7) ^ srow);   // inverse-swizzled source col

    // Each wave stages 8 K-rows and 8 V-rows per tile (one 16B chunk/lane).
    auto stage = [&](int buf, int kt) {
        const __bf16* srck = kg + (size_t)(kt * 64 + w * 8 + srow) * DHH + scol;
        __builtin_amdgcn_global_load_lds(
            (const __attribute__((address_space(1))) unsigned int*)srck,
            (__attribute__((address_space(3))) unsigned int*)&kv_lds[buf][0][w * 512],
            16, 0, 0);
        const __bf16* srcv = vg + (size_t)(w * 8 + srow) * SS + kt * 64 + scol;
        __builtin_amdgcn_global_load_lds(
            (const __attribute__((address_space(1))) unsigned int*)srcv,
            (__attribute__((address_space(3))) unsigned int*)&kv_lds[buf][1][w * 512],
            16, 0, 0);
    };

    stage(0, 0);
    __syncthreads();

    int cur = 0;
    for (int kt = 0; kt < NT; ++kt) {
        if (kt + 1 < NT) stage(cur ^ 1, kt + 1);   // issue-early prefetch

        const __bf16* kb = &kv_lds[cur][0][0];
        const __bf16* vb = &kv_lds[cur][1][0];
        const int sw = (lr & 7);                   // read-side swizzle key

        // ---- QK^T swapped: lane holds 16 log2-domain scores of its q-row
        f32x4 sc[4];
        __builtin_amdgcn_s_setprio(1);
#pragma unroll
        for (int cg = 0; cg < 4; ++cg) {
            int row = cg * 16 + lr;
            v8bf a0 = *reinterpret_cast<const v8bf*>(&kb[row * 64 + 8 * (lg ^ sw)]);
            v8bf a1 = *reinterpret_cast<const v8bf*>(&kb[row * 64 + 8 * ((4 + lg) ^ sw)]);
            f32x4 t = {0.f, 0.f, 0.f, 0.f};
            t = __builtin_amdgcn_mfma_f32_16x16x32_bf16(a0, qa0, t, 0, 0, 0);
            t = __builtin_amdgcn_mfma_f32_16x16x32_bf16(a1, qa1, t, 0, 0, 0);
            sc[cg] = t;
        }
        __builtin_amdgcn_s_setprio(0);

        // ---- lane-local online softmax in log2 domain, defer-max (THR=8)
        float mloc = sc[0][0];
#pragma unroll
        for (int cg = 0; cg < 4; ++cg)
#pragma unroll
            for (int r = 0; r < 4; ++r) mloc = fmaxf(mloc, sc[cg][r]);
        mloc = fmaxf(mloc, __shfl_xor(mloc, 16));
        mloc = fmaxf(mloc, __shfl_xor(mloc, 32));

        if (__any(mloc > m_run + 8.0f)) {
            float m_new = fmaxf(m_run, mloc);
            float corr  = exp2f(m_run - m_new);
            m_run = m_new;
            l_run *= corr;
            float cb[4];
#pragma unroll
            for (int r = 0; r < 4; ++r) cb[r] = __shfl(corr, lg * 4 + r);
#pragma unroll
            for (int cg = 0; cg < 4; ++cg)
#pragma unroll
                for (int r = 0; r < 4; ++r) acc[cg][r] *= cb[r];
        }

        float rs = 0.f;
#pragma unroll
        for (int cg = 0; cg < 4; ++cg) {
            float p0 = exp2f(sc[cg][0] - m_run);
            float p1 = exp2f(sc[cg][1] - m_run);
            float p2 = exp2f(sc[cg][2] - m_run);
            float p3 = exp2f(sc[cg][3] - m_run);
            rs += (p0 + p1) + (p2 + p3);
            uint2 u;
            u.x = pk2(p0, p1);
            u.y = pk2(p2, p3);
            // P[q][k]: q-row = w*16+lr, k = cg*16 + lg*4 + {0..3}
            *reinterpret_cast<uint2*>(&p_lds[w * 16 + lr][cg * 16 + lg * 4]) = u;
        }
        rs += __shfl_xor(rs, 16);
        rs += __shfl_xor(rs, 32);
        l_run += rs;

        // ---- PV: acc += P @ V
        v8bf pa0 = *reinterpret_cast<const v8bf*>(&p_lds[w * 16 + lr][lg * 8]);
        v8bf pa1 = *reinterpret_cast<const v8bf*>(&p_lds[w * 16 + lr][32 + lg * 8]);
        __builtin_amdgcn_s_setprio(1);
#pragma unroll
        for (int cg = 0; cg < 4; ++cg) {
            int row = cg * 16 + lr;
            v8bf b0 = *reinterpret_cast<const v8bf*>(&vb[row * 64 + 8 * (lg ^ sw)]);
            v8bf b1 = *reinterpret_cast<const v8bf*>(&vb[row * 64 + 8 * ((4 + lg) ^ sw)]);
            acc[cg] = __builtin_amdgcn_mfma_f32_16x16x32_bf16(pa0, b0, acc[cg], 0, 0, 0);
            acc[cg] = __builtin_amdgcn_mfma_f32_16x16x32_bf16(pa1, b1, acc[cg], 0, 0, 0);
        }
        __builtin_amdgcn_s_setprio(0);

        __syncthreads();   // drains prefetch + protects buffer reuse
        cur ^= 1;
    }

    // ---- epilogue
    float linv[4];
#pragma unroll
    for (int r = 0; r < 4; ++r) linv[r] = 1.0f / __shfl(l_run, lg * 4 + r);
#pragma unroll
    for (int cg = 0; cg < 4; ++cg)
#pragma unroll
        for (int r = 0; r < 4; ++r) {
            int sr = s0 + w * 16 + lg * 4 + r;
            int e  = cg * 16 + lr;
            out[((size_t)b * SS + sr) * DD + h * DHH + e] = acc[cg][r] * linv[r];
        }
}

// ---------------------------------------------------------------------------
extern "C" void kernel_launch(void* const* d_in, const int* in_sizes, int n_in,
                              void* d_out, int out_size, void* d_ws, size_t ws_size,
                              hipStream_t stream)
{
    const float* seqs = (const float*)d_in[0];
    const float* Wq   = (const float*)d_in[1];
    const float* bq   = (const float*)d_in[2];
    const float* Wk   = (const float*)d_in[3];
    const float* bk   = (const float*)d_in[4];
    const float* Wv   = (const float*)d_in[5];
    const float* bv   = (const float*)d_in[6];
    float* out = (float*)d_out;

    const size_t per = (size_t)BB * HH * SS * DHH;
    __bf16* q_ws  = (__bf16*)d_ws;
    __bf16* k_ws  = q_ws + per;
    __bf16* vt_ws = k_ws + per;

    dim3 gridp(BB * (SS / 64), HH);
    qkv_kernel<<<gridp, 256, 0, stream>>>(seqs, Wq, bq, Wk, bk, Wv, bv,
                                          q_ws, k_ws, vt_ws);
    dim3 gridf(SS / QBLK, BB * HH);
    flash_kernel<<<gridf, 512, 0, stream>>>(q_ws, k_ws, vt_ws, out);
}